// Round 15
// baseline (362.788 us; speedup 1.0000x reference)
//
#include <hip/hip_runtime.h>

// SelfAttn (SAGAN block): B=4, C=512, N=4096, C8=64
// out = gamma * (V @ softmax(Q K^T)^T) + x ; also outputs attention [B,N,N].
// R15: R13 structure, but att/out stores are PLAIN (L2-cached) instead of
// nontemporal. Theory: NT stores bypass L2 and ack at HBM (~3k cyc) with
// limited per-CU slots -> ~1-2 TB/s chip ceiling (matches R8-R13 write rates
// invariant across schedules). Plain stores ack at L2 (~200 cyc); L2->HBM
// drains asynchronously (fillBuffer: 6.9 TB/s at 10% occupancy).

#define BB 4
#define CC 512
#define NN 4096
#define C8V 64

typedef __bf16 bf16x8 __attribute__((ext_vector_type(8)));
typedef float f32x4 __attribute__((ext_vector_type(4)));
typedef float f32x4v __attribute__((ext_vector_type(4)));
typedef unsigned short u16x8 __attribute__((ext_vector_type(8)));

#if __has_builtin(__builtin_amdgcn_exp2f)
#define EXP2(x) __builtin_amdgcn_exp2f(x)
#else
#define EXP2(x) exp2f(x)
#endif

#define MFMA16(a, b, c) __builtin_amdgcn_mfma_f32_16x16x32_bf16((a), (b), (c), 0, 0, 0)

__device__ __forceinline__ unsigned short f2b(float f) {
  union { float f; unsigned u; } x; x.f = f;
  unsigned u = x.u;
  u += 0x7fffu + ((u >> 16) & 1u);   // RNE round to bf16
  return (unsigned short)(u >> 16);
}

__device__ __forceinline__ float b2f(unsigned short s) {
  union { unsigned u; float f; } x; x.u = ((unsigned)s) << 16;
  return x.f;
}

__device__ __forceinline__ bf16x8 ldb8(const unsigned short* p) {
  return *reinterpret_cast<const bf16x8*>(p);
}

// ---------------- weights fp32 -> bf16 ----------------
__global__ __launch_bounds__(256) void k_cvt_w(
    const float* __restrict__ wq, const float* __restrict__ wk, const float* __restrict__ wv,
    unsigned short* __restrict__ wqb, unsigned short* __restrict__ wkb, unsigned short* __restrict__ wvb) {
  int i = blockIdx.x * 256 + threadIdx.x;
  if (i < 32768)        wqb[i] = f2b(wq[i]);
  else if (i < 65536)   wkb[i - 32768] = f2b(wk[i - 32768]);
  else if (i < 327680)  wvb[i - 65536] = f2b(wv[i - 65536]);
}

// ---------------- transpose [C][N] f32 -> [N][C] bf16 (per batch) ----------------
__global__ __launch_bounds__(256) void k_transpose(const float* __restrict__ src,
                                                   unsigned short* __restrict__ dst) {
  __shared__ float tile[64][65];
  int b = blockIdx.z, c0 = blockIdx.y * 64, n0 = blockIdx.x * 64;
  const float* s = src + (size_t)b * CC * NN;
  unsigned short* d = dst + (size_t)b * NN * CC;
  int t = threadIdx.x;
#pragma unroll
  for (int j = 0; j < 4; j++) {
    int idx = t + j * 256, row = idx >> 4, col4 = (idx & 15) * 4;
    f32x4v v4 = *reinterpret_cast<const f32x4v*>(&s[(size_t)(c0 + row) * NN + n0 + col4]);
    tile[row][col4 + 0] = v4.x; tile[row][col4 + 1] = v4.y;
    tile[row][col4 + 2] = v4.z; tile[row][col4 + 3] = v4.w;
  }
  __syncthreads();
#pragma unroll
  for (int j = 0; j < 4; j++) {
    int idx = t + j * 256, nrow = idx >> 4, c4 = (idx & 15) * 4;
    ushort4 o;
    o.x = f2b(tile[c4 + 0][nrow]); o.y = f2b(tile[c4 + 1][nrow]);
    o.z = f2b(tile[c4 + 2][nrow]); o.w = f2b(tile[c4 + 3][nrow]);
    *reinterpret_cast<ushort4*>(&d[(size_t)(n0 + nrow) * CC + c0 + c4]) = o;
  }
}

// ---------------- Q/K projection ----------------
__global__ __launch_bounds__(256) void k_proj64(const unsigned short* __restrict__ aT,
                                                const unsigned short* __restrict__ wb,
                                                const float* __restrict__ bias,
                                                unsigned short* __restrict__ out, float scale) {
  int wave = threadIdx.x >> 6, l = threadIdx.x & 63;
  int r0 = blockIdx.x * 64 + wave * 16;
  int lr = l & 15, lk = l >> 4;
  const unsigned short* arow = aT + (size_t)(r0 + lr) * CC + lk * 8;
  f32x4 acc[4] = {};
  for (int ks = 0; ks < 16; ks++) {
    bf16x8 a = ldb8(arow + ks * 32);
#pragma unroll
    for (int cg = 0; cg < 4; cg++) {
      bf16x8 bfr = ldb8(wb + (size_t)(cg * 16 + lr) * CC + ks * 32 + lk * 8);
      acc[cg] = MFMA16(a, bfr, acc[cg]);
    }
  }
#pragma unroll
  for (int cg = 0; cg < 4; cg++) {
    int o = cg * 16 + lr;
    float bv = bias[o];
#pragma unroll
    for (int i = 0; i < 4; i++) {
      int row = r0 + lk * 4 + i;
      out[(size_t)row * C8V + o] = f2b((acc[cg][i] + bv) * scale);
    }
  }
}

// ---------------- V projection ----------------
__global__ __launch_bounds__(256) void k_projv(const unsigned short* __restrict__ wvb,
                                               const unsigned short* __restrict__ xT,
                                               const float* __restrict__ bv,
                                               unsigned short* __restrict__ v) {
  int b = blockIdx.z, c0 = blockIdx.y * 64;
  int wave = threadIdx.x >> 6, l = threadIdx.x & 63;
  int n0 = blockIdx.x * 256 + wave * 64;
  int lr = l & 15, lk = l >> 4;
  const unsigned short* xb = xT + (size_t)b * NN * CC;
  f32x4 acc[4][4] = {};
  for (int ks = 0; ks < 16; ks++) {
    bf16x8 a[4], bfr[4];
#pragma unroll
    for (int rg = 0; rg < 4; rg++)
      a[rg] = ldb8(wvb + (size_t)(c0 + rg * 16 + lr) * CC + ks * 32 + lk * 8);
#pragma unroll
    for (int cg = 0; cg < 4; cg++)
      bfr[cg] = ldb8(xb + (size_t)(n0 + cg * 16 + lr) * CC + ks * 32 + lk * 8);
#pragma unroll
    for (int rg = 0; rg < 4; rg++)
#pragma unroll
      for (int cg = 0; cg < 4; cg++)
        acc[rg][cg] = MFMA16(a[rg], bfr[cg], acc[rg][cg]);
  }
  unsigned short* vb = v + (size_t)b * CC * NN;
#pragma unroll
  for (int rg = 0; rg < 4; rg++)
#pragma unroll
    for (int i = 0; i < 4; i++) {
      int row = c0 + rg * 16 + lk * 4 + i;
      float bias = bv[row];
#pragma unroll
      for (int cg = 0; cg < 4; cg++) {
        int col = n0 + cg * 16 + lr;
        vb[(size_t)row * NN + col] = f2b(acc[rg][cg][i] + bias);
      }
    }
}

// ---------------- softmax inverse-denominator: inv[b*N + row] ----------------
__global__ __launch_bounds__(512) void k_sminv(const unsigned short* __restrict__ q,
                                               const unsigned short* __restrict__ kt,
                                               float* __restrict__ invp) {
  __shared__ float psum[8][16];
  int b = blockIdx.y;
  int w = threadIdx.x >> 6, l = threadIdx.x & 63;
  int rg = w >> 2, cq = w & 3;
  int r0 = blockIdx.x * 32 + rg * 16;
  int lr = l & 15, lk = l >> 4;
  const unsigned short* qp = q + (size_t)(b * NN + r0 + lr) * C8V + lk * 8;
  bf16x8 aq0 = ldb8(qp);
  bf16x8 aq1 = ldb8(qp + 32);
  const unsigned short* ktb = kt + (size_t)b * NN * C8V;
  int jt0 = cq * 16;

  float lsum[4] = {0.f, 0.f, 0.f, 0.f};
  for (int jt = jt0; jt < jt0 + 16; jt++) {
    f32x4 acc[4] = {};
#pragma unroll
    for (int cg = 0; cg < 4; cg++) {
      const unsigned short* kp = ktb + (size_t)(jt * 64 + cg * 16 + lr) * C8V + lk * 8;
      acc[cg] = MFMA16(aq0, ldb8(kp), acc[cg]);
      acc[cg] = MFMA16(aq1, ldb8(kp + 32), acc[cg]);
    }
#pragma unroll
    for (int i = 0; i < 4; i++)
      lsum[i] += (EXP2(acc[0][i]) + EXP2(acc[1][i])) + (EXP2(acc[2][i]) + EXP2(acc[3][i]));
  }
#pragma unroll
  for (int i = 0; i < 4; i++) {
#pragma unroll
    for (int mm = 1; mm < 16; mm <<= 1) lsum[i] += __shfl_xor(lsum[i], mm);
  }
  if (lr == 0) {
#pragma unroll
    for (int i = 0; i < 4; i++) psum[w][lk * 4 + i] = lsum[i];
  }
  __syncthreads();
  if (cq == 0 && lr == 0) {
#pragma unroll
    for (int i = 0; i < 4; i++) {
      int rr = lk * 4 + i;
      float s = psum[rg * 4 + 0][rr] + psum[rg * 4 + 1][rr] +
                psum[rg * 4 + 2][rr] + psum[rg * 4 + 3][rr];
      invp[(size_t)b * NN + r0 + rr] = 1.0f / s;
    }
  }
}

// ---------------- fused: energy recompute + att write + PV + epilogue ----------------
// R13 pipeline (FIFO-clean, register double-buffered kt/v, lgkm-only
// barriers), stores now PLAIN so they ack at L2 and drain asynchronously.
__global__ __launch_bounds__(512, 2) void k_fused(const unsigned short* __restrict__ q,
                                                  const unsigned short* __restrict__ kt,
                                                  const unsigned short* __restrict__ v,
                                                  const float* __restrict__ invp,
                                                  const float* __restrict__ x,
                                                  const float* __restrict__ gamma,
                                                  float* __restrict__ out,
                                                  float* __restrict__ att) {
  __shared__ unsigned short smP[2][64 * 64];   // 2 x 8 KiB P tiles

  int bid = blockIdx.x;
  int b = (bid & 7) >> 1;                       // XCD id = bid % 8
  int m0 = ((bid >> 3) * 2 + (bid & 1)) * 64;   // 64 m-tiles per batch
  int t = threadIdx.x, w = t >> 6, l = t & 63, lr = l & 15, lk = l >> 4;
  int rg = w >> 1, nh = w & 1;                  // QK^T: rows rg*16.., col-half nh
  int c0w = w * 64;                             // PV: 64 c-rows per wave
  int mrow = t >> 3, col8 = t & 7;              // ATTST: row, col-octet

  const unsigned short* ktb = kt + (size_t)b * NN * C8V;
  const unsigned short* vb = v + (size_t)b * CC * NN;
  float* ab = att + (size_t)b * NN * NN;

  const unsigned short* qp = q + (size_t)(b * NN + m0 + rg * 16 + lr) * C8V + lk * 8;
  bf16x8 aq0 = ldb8(qp), aq1 = ldb8(qp + 32);
  f32x4v invv = *reinterpret_cast<const f32x4v*>(&invp[(size_t)b * NN + m0 + rg * 16 + lk * 4]);

#define LDKT(D, JT)                                                            \
  _Pragma("unroll")                                                            \
  for (int cg = 0; cg < 2; cg++) {                                             \
    const unsigned short* kp =                                                 \
        ktb + (size_t)((JT) * 64 + nh * 32 + cg * 16 + lr) * C8V + lk * 8;     \
    D[cg * 2] = ldb8(kp);                                                      \
    D[cg * 2 + 1] = ldb8(kp + 32);                                             \
  }

#define LDV(D, JT)                                                             \
  _Pragma("unroll")                                                            \
  for (int rg2 = 0; rg2 < 4; rg2++) {                                          \
    const unsigned short* vp =                                                 \
        vb + (size_t)(c0w + rg2 * 16 + lr) * NN + (JT) * 64 + lk * 8;          \
    D[rg2 * 2] = ldb8(vp);                                                     \
    D[rg2 * 2 + 1] = ldb8(vp + 32);                                            \
  }

// QK^T from REGISTER kt set -> softmax -> bf16 P into LDS buf (no globals)
#define QKSM(KT, BUF)                                                          \
  {                                                                            \
    char* pbuf = reinterpret_cast<char*>(&smP[BUF][0]);                        \
    _Pragma("unroll")                                                          \
    for (int cg = 0; cg < 2; cg++) {                                           \
      f32x4 z = {};                                                            \
      z = MFMA16(aq0, KT[cg * 2], z);                                          \
      z = MFMA16(aq1, KT[cg * 2 + 1], z);                                      \
      int nl = nh * 32 + cg * 16 + lr;                                         \
      _Pragma("unroll")                                                        \
      for (int i = 0; i < 4; i++) {                                            \
        int ml = rg * 16 + lk * 4 + i;                                         \
        float p = EXP2(z[i]) * invv[i];                                        \
        *reinterpret_cast<unsigned short*>(                                    \
            pbuf + ml * 128 + ((nl * 2) ^ ((ml & 7) << 4))) = f2b(p);          \
      }                                                                        \
    }                                                                          \
  }

// att store: LDS P readback -> fp32 -> 2x dwordx4 PLAIN store (via L2)
#define ATTST(BUF, JT)                                                         \
  {                                                                            \
    const char* pr = reinterpret_cast<const char*>(&smP[BUF][0]);              \
    u16x8 raw = *reinterpret_cast<const u16x8*>(                               \
        pr + mrow * 128 + ((col8 * 16) ^ ((mrow & 7) << 4)));                  \
    f32x4v lo, hi;                                                             \
    lo.x = b2f(raw[0]); lo.y = b2f(raw[1]); lo.z = b2f(raw[2]);                \
    lo.w = b2f(raw[3]); hi.x = b2f(raw[4]); hi.y = b2f(raw[5]);                \
    hi.z = b2f(raw[6]); hi.w = b2f(raw[7]);                                    \
    float* dst = &ab[(size_t)(m0 + mrow) * NN + (JT) * 64 + col8 * 8];         \
    *reinterpret_cast<f32x4v*>(dst) = lo;                                      \
    *reinterpret_cast<f32x4v*>(dst + 4) = hi;                                  \
  }

#define PV(VR, BUF)                                                            \
  {                                                                            \
    const char* pr = reinterpret_cast<const char*>(&smP[BUF][0]);              \
    __builtin_amdgcn_s_setprio(1);                                             \
    _Pragma("unroll")                                                          \
    for (int ks = 0; ks < 2; ks++) {                                           \
      bf16x8 bfr[4];                                                           \
      _Pragma("unroll")                                                        \
      for (int cg = 0; cg < 4; cg++) {                                         \
        int mr = cg * 16 + lr;                                                 \
        bfr[cg] = *reinterpret_cast<const bf16x8*>(                            \
            pr + mr * 128 + ((ks * 64 + lk * 16) ^ ((mr & 7) << 4)));          \
      }                                                                        \
      _Pragma("unroll")                                                        \
      for (int rg2 = 0; rg2 < 4; rg2++)                                        \
        _Pragma("unroll")                                                      \
        for (int cg = 0; cg < 4; cg++)                                         \
          acc[rg2][cg] = MFMA16(VR[rg2 * 2 + ks], bfr[cg], acc[rg2][cg]);      \
    }                                                                          \
    __builtin_amdgcn_s_setprio(0);                                             \
  }

#define SB() __builtin_amdgcn_sched_barrier(0);

#define SYNC_NODRAIN()                                   \
  asm volatile("s_waitcnt lgkmcnt(0)" ::: "memory");     \
  __builtin_amdgcn_s_barrier();                          \
  __builtin_amdgcn_sched_barrier(0);

  f32x4 acc[4][4] = {};
  bf16x8 ktA[4], ktB[4];   // kt sets: even chunks -> A, odd -> B
  bf16x8 vA[8], vB[8];     // v sets: even chunks -> A, odd -> B

  // prologue: kt(0)->A, v(0)->A, P(0)->buf0, kt(1)->B
  LDKT(ktA, 0);
  LDV(vA, 0);
  QKSM(ktA, 0);            // consumes ktA (no stores older -> clean wait)
  LDKT(ktB, 1);
  SYNC_NODRAIN();

// one period; CUR = chunk parity of g
#define BODY(G, KTF, VN, KTC, VC, CUR)                                         \
  {                                                                            \
    int g = (G);                                                               \
    if (g < 62) LDKT(KTF, g + 2);        /* loads FIRST */                     \
    if (g < 63) LDV(VN, g + 1);                                                \
    SB();                                                                      \
    ATTST(CUR, g);                       /* stores after loads */              \
    SB();                                                                      \
    if (g < 63) QKSM(KTC, (CUR) ^ 1);    /* reg MFMA + LDS write */            \
    PV(VC, CUR);                                                               \
    SYNC_NODRAIN();                                                            \
  }

  for (int g2 = 0; g2 < 64; g2 += 2) {
    BODY(g2,     ktA, vB, ktB, vA, 0);   // even: fetch kt(g+2)->A, v(g+1)->B; QK from B; PV from A
    BODY(g2 + 1, ktB, vA, ktA, vB, 1);   // odd: mirrored
  }
#undef LDKT
#undef LDV
#undef QKSM
#undef ATTST
#undef PV
#undef SB
#undef SYNC_NODRAIN
#undef BODY

  // ---- epilogue: out = gamma*acc + x (plain stores via L2) ----
  float gm = gamma[0];
  const float* xb = x + (size_t)b * CC * NN;
  float* ob = out + (size_t)b * CC * NN;
#pragma unroll
  for (int rg2 = 0; rg2 < 4; rg2++)
#pragma unroll
    for (int i = 0; i < 4; i++) {
      int row = c0w + rg2 * 16 + lk * 4 + i;
#pragma unroll
      for (int cg = 0; cg < 4; cg++) {
        int col = m0 + cg * 16 + lr;
        size_t off = (size_t)row * NN + col;
        float xv = __builtin_nontemporal_load(&xb[off]);
        ob[off] = gm * acc[rg2][cg][i] + xv;
      }
    }
}

extern "C" void kernel_launch(void* const* d_in, const int* in_sizes, int n_in,
                              void* d_out, int out_size, void* d_ws, size_t ws_size,
                              hipStream_t stream) {
  const float* x  = (const float*)d_in[0];
  const float* y  = (const float*)d_in[1];
  const float* wq = (const float*)d_in[2];
  const float* bq = (const float*)d_in[3];
  const float* wk = (const float*)d_in[4];
  const float* bk = (const float*)d_in[5];
  const float* wv = (const float*)d_in[6];
  const float* bv = (const float*)d_in[7];
  const float* gamma = (const float*)d_in[8];

  float* out = (float*)d_out;
  float* att = out + (size_t)BB * CC * NN;   // attention region of d_out

  // workspace layout (bytes)
  char* ws = (char*)d_ws;
  unsigned short* yT  = (unsigned short*)(ws);                 // 16 MiB  [B][N][C] bf16
  unsigned short* xT  = (unsigned short*)(ws + 16777216);      // 16 MiB
  unsigned short* q   = (unsigned short*)(ws + 33554432);      // 2 MiB   [B*N][64]
  unsigned short* kt  = (unsigned short*)(ws + 35651584);      // 2 MiB   [B*N][64]
  unsigned short* v   = (unsigned short*)(ws + 37748736);      // 16 MiB  [B][C][N]
  unsigned short* wqb = (unsigned short*)(ws + 54525952);      // 64 KiB
  unsigned short* wkb = (unsigned short*)(ws + 54591488);      // 64 KiB
  unsigned short* wvb = (unsigned short*)(ws + 54657024);      // 512 KiB
  float*          inv = (float*)(ws + 55181312);               // 64 KiB  [B*N]
  if (ws_size < 55246848u) return;  // insufficient scratch -> fail loudly

  k_cvt_w<<<1280, 256, 0, stream>>>(wq, wk, wv, wqb, wkb, wvb);
  k_transpose<<<dim3(64, 8, 4), 256, 0, stream>>>(y, yT);
  k_transpose<<<dim3(64, 8, 4), 256, 0, stream>>>(x, xT);
  k_proj64<<<256, 256, 0, stream>>>(yT, wqb, bq, q, 1.44269504088896f);  // q pre-scaled by log2(e)
  k_proj64<<<256, 256, 0, stream>>>(yT, wkb, bk, kt, 1.0f);
  k_projv<<<dim3(16, 8, 4), 256, 0, stream>>>(wvb, xT, bv, v);
  k_sminv<<<dim3(128, 4), 512, 0, stream>>>(q, kt, inv);
  k_fused<<<256, 512, 0, stream>>>(q, kt, v, inv, x, gamma, out, att);
}

// Round 16
// 259.588 us; speedup vs baseline: 1.3976x; 1.3976x over previous
//
#include <hip/hip_runtime.h>

// SelfAttn (SAGAN block): B=4, C=512, N=4096, C8=64
// out = gamma * (V @ softmax(Q K^T)^T) + x ; also outputs attention [B,N,N].
// R16: (1) kt/v repacked so every hot fragment load is 1KB fully contiguous
// (was 16 half-lines per instr); (2) prologue fused: q+kt straight from y,
// packed v straight from x (transposes + yT/xT eliminated).

#define BB 4
#define CC 512
#define NN 4096
#define C8V 64

typedef __bf16 bf16x8 __attribute__((ext_vector_type(8)));
typedef float f32x4 __attribute__((ext_vector_type(4)));
typedef float f32x4v __attribute__((ext_vector_type(4)));
typedef unsigned short u16x8 __attribute__((ext_vector_type(8)));

#if __has_builtin(__builtin_amdgcn_exp2f)
#define EXP2(x) __builtin_amdgcn_exp2f(x)
#else
#define EXP2(x) exp2f(x)
#endif

#define MFMA16(a, b, c) __builtin_amdgcn_mfma_f32_16x16x32_bf16((a), (b), (c), 0, 0, 0)

__device__ __forceinline__ unsigned short f2b(float f) {
  union { float f; unsigned u; } x; x.f = f;
  unsigned u = x.u;
  u += 0x7fffu + ((u >> 16) & 1u);   // RNE round to bf16
  return (unsigned short)(u >> 16);
}

__device__ __forceinline__ float b2f(unsigned short s) {
  union { unsigned u; float f; } x; x.u = ((unsigned)s) << 16;
  return x.f;
}

__device__ __forceinline__ bf16x8 ldb8(const unsigned short* p) {
  return *reinterpret_cast<const bf16x8*>(p);
}

// ---------------- weights fp32 -> bf16 ----------------
__global__ __launch_bounds__(256) void k_cvt_w(
    const float* __restrict__ wq, const float* __restrict__ wk, const float* __restrict__ wv,
    unsigned short* __restrict__ wqb, unsigned short* __restrict__ wkb, unsigned short* __restrict__ wvb) {
  int i = blockIdx.x * 256 + threadIdx.x;
  if (i < 32768)        wqb[i] = f2b(wq[i]);
  else if (i < 65536)   wkb[i - 32768] = f2b(wk[i - 32768]);
  else if (i < 327680)  wvb[i - 65536] = f2b(wv[i - 65536]);
}

// ---------------- q + kt projection, straight from y ----------------
// Block: 64-n tile x batch, 256 thr (4 waves, wave w = 16 n-rows).
// Per 128-c slab: stage y[c][n] -> LDS transposed [n][c] bf16, then
// A-frag = ytile rows (n, k=c), B-frag = w rows (o, k=c) from L2.
// Outputs: q [b*N][64] (pre-scaled by log2e), kt PACKED
// [b][n>>4][o>>5][n&15][o&31] so consumers load 1KB contiguous.
__global__ __launch_bounds__(256) void k_projqk(
    const float* __restrict__ y,
    const unsigned short* __restrict__ wqb, const unsigned short* __restrict__ wkb,
    const float* __restrict__ bq, const float* __restrict__ bk,
    unsigned short* __restrict__ q, unsigned short* __restrict__ ktp) {
  __shared__ unsigned short ytile[64][130];
  int b = blockIdx.y, n0 = blockIdx.x * 64;
  int t = threadIdx.x, w = t >> 6, l = t & 63, lr = l & 15, lk = l >> 4;
  const float* yb = y + (size_t)b * CC * NN;

  f32x4 qacc[4] = {}, kacc[4] = {};
  for (int slab = 0; slab < 4; slab++) {
    int cs = slab * 128;
#pragma unroll
    for (int r = 0; r < 8; r++) {                 // stage 128c x 64n
      int idx = t + r * 256, c = idx >> 4, n4 = (idx & 15) * 4;
      f32x4v v4 = *reinterpret_cast<const f32x4v*>(&yb[(size_t)(cs + c) * NN + n0 + n4]);
      ytile[n4 + 0][c] = f2b(v4.x); ytile[n4 + 1][c] = f2b(v4.y);
      ytile[n4 + 2][c] = f2b(v4.z); ytile[n4 + 3][c] = f2b(v4.w);
    }
    __syncthreads();
#pragma unroll
    for (int ks = 0; ks < 4; ks++) {
      bf16x8 a = *reinterpret_cast<const bf16x8*>(&ytile[w * 16 + lr][ks * 32 + lk * 8]);
      int cgl = cs + ks * 32 + lk * 8;
#pragma unroll
      for (int cg = 0; cg < 4; cg++) {
        qacc[cg] = MFMA16(a, ldb8(wqb + (size_t)(cg * 16 + lr) * CC + cgl), qacc[cg]);
        kacc[cg] = MFMA16(a, ldb8(wkb + (size_t)(cg * 16 + lr) * CC + cgl), kacc[cg]);
      }
    }
    __syncthreads();
  }
#pragma unroll
  for (int cg = 0; cg < 4; cg++) {
    int o = cg * 16 + lr;
    float bqv = bq[o], bkv = bk[o];
#pragma unroll
    for (int i = 0; i < 4; i++) {
      int n = n0 + w * 16 + lk * 4 + i;
      q[(size_t)(b * NN + n) * C8V + o] = f2b((qacc[cg][i] + bqv) * 1.44269504088896f);
      ktp[((size_t)(b * 256 + (n >> 4)) * 2 + (o >> 5)) * 512 + (n & 15) * 32 + (o & 31)] =
          f2b(kacc[cg][i] + bkv);
    }
  }
}

// ---------------- v projection, straight from x, packed output ----------------
// Block: 64-n tile x batch, 512 thr (8 waves, wave w = 64 c-rows).
// v PACKED [b][n>>6][(n>>5)&1][c][n&31] -> consumers load 1KB contiguous.
__global__ __launch_bounds__(512) void k_projv(
    const float* __restrict__ x, const unsigned short* __restrict__ wvb,
    const float* __restrict__ bv, unsigned short* __restrict__ vp) {
  __shared__ unsigned short xtile[64][130];
  int b = blockIdx.y, n0 = blockIdx.x * 64;
  int t = threadIdx.x, w = t >> 6, l = t & 63, lr = l & 15, lk = l >> 4;
  const float* xb = x + (size_t)b * CC * NN;
  int c0w = w * 64;

  f32x4 acc[4][4] = {};
  for (int slab = 0; slab < 4; slab++) {
    int cs = slab * 128;
#pragma unroll
    for (int r = 0; r < 4; r++) {                 // stage 128c x 64n
      int idx = t + r * 512, c = idx >> 4, n4 = (idx & 15) * 4;
      f32x4v v4 = *reinterpret_cast<const f32x4v*>(&xb[(size_t)(cs + c) * NN + n0 + n4]);
      xtile[n4 + 0][c] = f2b(v4.x); xtile[n4 + 1][c] = f2b(v4.y);
      xtile[n4 + 2][c] = f2b(v4.z); xtile[n4 + 3][c] = f2b(v4.w);
    }
    __syncthreads();
#pragma unroll
    for (int ks = 0; ks < 4; ks++) {
      bf16x8 bfr[4];
#pragma unroll
      for (int cg = 0; cg < 4; cg++)
        bfr[cg] = *reinterpret_cast<const bf16x8*>(&xtile[cg * 16 + lr][ks * 32 + lk * 8]);
#pragma unroll
      for (int rg = 0; rg < 4; rg++) {
        bf16x8 a = ldb8(wvb + (size_t)(c0w + rg * 16 + lr) * CC + cs + ks * 32 + lk * 8);
#pragma unroll
        for (int cg = 0; cg < 4; cg++)
          acc[rg][cg] = MFMA16(a, bfr[cg], acc[rg][cg]);
      }
    }
    __syncthreads();
  }
#pragma unroll
  for (int rg = 0; rg < 4; rg++)
#pragma unroll
    for (int i = 0; i < 4; i++) {
      int c = c0w + rg * 16 + lk * 4 + i;
      float bias = bv[c];
#pragma unroll
      for (int cg = 0; cg < 4; cg++) {
        int n = n0 + cg * 16 + lr;
        vp[((size_t)(b * 64 + (n >> 6)) * 2 + ((n >> 5) & 1)) * 16384 + c * 32 + (n & 31)] =
            f2b(acc[rg][cg][i] + bias);
      }
    }
}

// ---------------- softmax inverse-denominator: inv[b*N + row] ----------------
// kt loads now 1KB contiguous per instruction (packed layout).
__global__ __launch_bounds__(512) void k_sminv(const unsigned short* __restrict__ q,
                                               const unsigned short* __restrict__ ktp,
                                               float* __restrict__ invp) {
  __shared__ float psum[8][16];
  int b = blockIdx.y;
  int w = threadIdx.x >> 6, l = threadIdx.x & 63;
  int rg = w >> 2, cq = w & 3;
  int r0 = blockIdx.x * 32 + rg * 16;
  int lr = l & 15, lk = l >> 4;
  const unsigned short* qp = q + (size_t)(b * NN + r0 + lr) * C8V + lk * 8;
  bf16x8 aq0 = ldb8(qp);
  bf16x8 aq1 = ldb8(qp + 32);
  int jt0 = cq * 16;

  float lsum[4] = {0.f, 0.f, 0.f, 0.f};
  for (int jt = jt0; jt < jt0 + 16; jt++) {
    f32x4 acc[4] = {};
#pragma unroll
    for (int cg = 0; cg < 4; cg++) {
      size_t base = ((size_t)(b * 256 + jt * 4 + cg) * 2) * 512 + lr * 32 + lk * 8;
      acc[cg] = MFMA16(aq0, ldb8(ktp + base), acc[cg]);
      acc[cg] = MFMA16(aq1, ldb8(ktp + base + 512), acc[cg]);
    }
#pragma unroll
    for (int i = 0; i < 4; i++)
      lsum[i] += (EXP2(acc[0][i]) + EXP2(acc[1][i])) + (EXP2(acc[2][i]) + EXP2(acc[3][i]));
  }
#pragma unroll
  for (int i = 0; i < 4; i++) {
#pragma unroll
    for (int mm = 1; mm < 16; mm <<= 1) lsum[i] += __shfl_xor(lsum[i], mm);
  }
  if (lr == 0) {
#pragma unroll
    for (int i = 0; i < 4; i++) psum[w][lk * 4 + i] = lsum[i];
  }
  __syncthreads();
  if (cq == 0 && lr == 0) {
#pragma unroll
    for (int i = 0; i < 4; i++) {
      int rr = lk * 4 + i;
      float s = psum[rg * 4 + 0][rr] + psum[rg * 4 + 1][rr] +
                psum[rg * 4 + 2][rr] + psum[rg * 4 + 3][rr];
      invp[(size_t)b * NN + r0 + rr] = 1.0f / s;
    }
  }
}

// ---------------- fused: energy recompute + att write + PV + epilogue ----------------
// R15 pipeline (FIFO-clean, register double-buffered kt/v, lgkm-only
// barriers, plain stores); kt/v loads now 1KB contiguous (packed layouts).
__global__ __launch_bounds__(512, 2) void k_fused(const unsigned short* __restrict__ q,
                                                  const unsigned short* __restrict__ ktp,
                                                  const unsigned short* __restrict__ vp,
                                                  const float* __restrict__ invp,
                                                  const float* __restrict__ x,
                                                  const float* __restrict__ gamma,
                                                  float* __restrict__ out,
                                                  float* __restrict__ att) {
  __shared__ unsigned short smP[2][64 * 64];   // 2 x 8 KiB P tiles

  int bid = blockIdx.x;
  int b = (bid & 7) >> 1;                       // XCD id = bid % 8
  int m0 = ((bid >> 3) * 2 + (bid & 1)) * 64;   // 64 m-tiles per batch
  int t = threadIdx.x, w = t >> 6, l = t & 63, lr = l & 15, lk = l >> 4;
  int rg = w >> 1, nh = w & 1;                  // QK^T: rows rg*16.., col-half nh
  int c0w = w * 64;                             // PV: 64 c-rows per wave
  int mrow = t >> 3, col8 = t & 7;              // ATTST: row, col-octet

  float* ab = att + (size_t)b * NN * NN;

  const unsigned short* qp = q + (size_t)(b * NN + m0 + rg * 16 + lr) * C8V + lk * 8;
  bf16x8 aq0 = ldb8(qp), aq1 = ldb8(qp + 32);
  f32x4v invv = *reinterpret_cast<const f32x4v*>(&invp[(size_t)b * NN + m0 + rg * 16 + lk * 4]);

#define LDKT(D, JT)                                                            \
  _Pragma("unroll")                                                            \
  for (int cg = 0; cg < 2; cg++) {                                             \
    size_t base = ((size_t)(b * 256 + (JT) * 4 + nh * 2 + cg) * 2) * 512 +     \
                  lr * 32 + lk * 8;                                            \
    D[cg * 2] = ldb8(ktp + base);                                              \
    D[cg * 2 + 1] = ldb8(ktp + base + 512);                                    \
  }

#define LDV(D, JT)                                                             \
  _Pragma("unroll")                                                            \
  for (int rg2 = 0; rg2 < 4; rg2++) {                                          \
    size_t vbase = ((size_t)(b * 64 + (JT)) * 2) * 16384 +                     \
                   (c0w + rg2 * 16 + lr) * 32 + lk * 8;                        \
    D[rg2 * 2] = ldb8(vp + vbase);                                             \
    D[rg2 * 2 + 1] = ldb8(vp + vbase + 16384);                                 \
  }

// QK^T from REGISTER kt set -> softmax -> bf16 P into LDS buf (no globals)
#define QKSM(KT, BUF)                                                          \
  {                                                                            \
    char* pbuf = reinterpret_cast<char*>(&smP[BUF][0]);                        \
    _Pragma("unroll")                                                          \
    for (int cg = 0; cg < 2; cg++) {                                           \
      f32x4 z = {};                                                            \
      z = MFMA16(aq0, KT[cg * 2], z);                                          \
      z = MFMA16(aq1, KT[cg * 2 + 1], z);                                      \
      int nl = nh * 32 + cg * 16 + lr;                                         \
      _Pragma("unroll")                                                        \
      for (int i = 0; i < 4; i++) {                                            \
        int ml = rg * 16 + lk * 4 + i;                                         \
        float p = EXP2(z[i]) * invv[i];                                        \
        *reinterpret_cast<unsigned short*>(                                    \
            pbuf + ml * 128 + ((nl * 2) ^ ((ml & 7) << 4))) = f2b(p);          \
      }                                                                        \
    }                                                                          \
  }

// att store: LDS P readback -> fp32 -> 2x dwordx4 PLAIN store (via L2)
#define ATTST(BUF, JT)                                                         \
  {                                                                            \
    const char* pr = reinterpret_cast<const char*>(&smP[BUF][0]);              \
    u16x8 raw = *reinterpret_cast<const u16x8*>(                               \
        pr + mrow * 128 + ((col8 * 16) ^ ((mrow & 7) << 4)));                  \
    f32x4v lo, hi;                                                             \
    lo.x = b2f(raw[0]); lo.y = b2f(raw[1]); lo.z = b2f(raw[2]);                \
    lo.w = b2f(raw[3]); hi.x = b2f(raw[4]); hi.y = b2f(raw[5]);                \
    hi.z = b2f(raw[6]); hi.w = b2f(raw[7]);                                    \
    float* dst = &ab[(size_t)(m0 + mrow) * NN + (JT) * 64 + col8 * 8];         \
    *reinterpret_cast<f32x4v*>(dst) = lo;                                      \
    *reinterpret_cast<f32x4v*>(dst + 4) = hi;                                  \
  }

#define PV(VR, BUF)                                                            \
  {                                                                            \
    const char* pr = reinterpret_cast<const char*>(&smP[BUF][0]);              \
    __builtin_amdgcn_s_setprio(1);                                             \
    _Pragma("unroll")                                                          \
    for (int ks = 0; ks < 2; ks++) {                                           \
      bf16x8 bfr[4];                                                           \
      _Pragma("unroll")                                                        \
      for (int cg = 0; cg < 4; cg++) {                                         \
        int mr = cg * 16 + lr;                                                 \
        bfr[cg] = *reinterpret_cast<const bf16x8*>(                            \
            pr + mr * 128 + ((ks * 64 + lk * 16) ^ ((mr & 7) << 4)));          \
      }                                                                        \
      _Pragma("unroll")                                                        \
      for (int rg2 = 0; rg2 < 4; rg2++)                                        \
        _Pragma("unroll")                                                      \
        for (int cg = 0; cg < 4; cg++)                                         \
          acc[rg2][cg] = MFMA16(VR[rg2 * 2 + ks], bfr[cg], acc[rg2][cg]);      \
    }                                                                          \
    __builtin_amdgcn_s_setprio(0);                                             \
  }

#define SB() __builtin_amdgcn_sched_barrier(0);

#define SYNC_NODRAIN()                                   \
  asm volatile("s_waitcnt lgkmcnt(0)" ::: "memory");     \
  __builtin_amdgcn_s_barrier();                          \
  __builtin_amdgcn_sched_barrier(0);

  f32x4 acc[4][4] = {};
  bf16x8 ktA[4], ktB[4];   // kt sets: even chunks -> A, odd -> B
  bf16x8 vA[8], vB[8];     // v sets: even chunks -> A, odd -> B

  // prologue: kt(0)->A, v(0)->A, P(0)->buf0, kt(1)->B
  LDKT(ktA, 0);
  LDV(vA, 0);
  QKSM(ktA, 0);
  LDKT(ktB, 1);
  SYNC_NODRAIN();

// one period; CUR = chunk parity of g
#define BODY(G, KTF, VN, KTC, VC, CUR)                                         \
  {                                                                            \
    int g = (G);                                                               \
    if (g < 62) LDKT(KTF, g + 2);        /* loads FIRST */                     \
    if (g < 63) LDV(VN, g + 1);                                                \
    SB();                                                                      \
    ATTST(CUR, g);                       /* stores after loads */              \
    SB();                                                                      \
    if (g < 63) QKSM(KTC, (CUR) ^ 1);    /* reg MFMA + LDS write */            \
    PV(VC, CUR);                                                               \
    SYNC_NODRAIN();                                                            \
  }

  for (int g2 = 0; g2 < 64; g2 += 2) {
    BODY(g2,     ktA, vB, ktB, vA, 0);
    BODY(g2 + 1, ktB, vA, ktA, vB, 1);
  }
#undef LDKT
#undef LDV
#undef QKSM
#undef ATTST
#undef PV
#undef SB
#undef SYNC_NODRAIN
#undef BODY

  // ---- epilogue: out = gamma*acc + x (plain stores via L2) ----
  float gm = gamma[0];
  const float* xb = x + (size_t)b * CC * NN;
  float* ob = out + (size_t)b * CC * NN;
#pragma unroll
  for (int rg2 = 0; rg2 < 4; rg2++)
#pragma unroll
    for (int i = 0; i < 4; i++) {
      int row = c0w + rg2 * 16 + lk * 4 + i;
#pragma unroll
      for (int cg = 0; cg < 4; cg++) {
        int col = m0 + cg * 16 + lr;
        size_t off = (size_t)row * NN + col;
        float xv = __builtin_nontemporal_load(&xb[off]);
        ob[off] = gm * acc[rg2][cg][i] + xv;
      }
    }
}

extern "C" void kernel_launch(void* const* d_in, const int* in_sizes, int n_in,
                              void* d_out, int out_size, void* d_ws, size_t ws_size,
                              hipStream_t stream) {
  const float* x  = (const float*)d_in[0];
  const float* y  = (const float*)d_in[1];
  const float* wq = (const float*)d_in[2];
  const float* bq = (const float*)d_in[3];
  const float* wk = (const float*)d_in[4];
  const float* bk = (const float*)d_in[5];
  const float* wv = (const float*)d_in[6];
  const float* bv = (const float*)d_in[7];
  const float* gamma = (const float*)d_in[8];

  float* out = (float*)d_out;
  float* att = out + (size_t)BB * CC * NN;   // attention region of d_out

  // workspace layout (bytes)
  char* ws = (char*)d_ws;
  unsigned short* q   = (unsigned short*)(ws);                 // 2 MiB  [b*N][64]
  unsigned short* ktp = (unsigned short*)(ws + 2097152);       // 2 MiB  packed kt
  unsigned short* vp  = (unsigned short*)(ws + 4194304);       // 16 MiB packed v
  unsigned short* wqb = (unsigned short*)(ws + 20971520);      // 64 KiB
  unsigned short* wkb = (unsigned short*)(ws + 21037056);      // 64 KiB
  unsigned short* wvb = (unsigned short*)(ws + 21102592);      // 512 KiB
  float*          inv = (float*)(ws + 21626880);               // 64 KiB [b*N]
  if (ws_size < 21692416u) return;  // insufficient scratch -> fail loudly

  k_cvt_w<<<1280, 256, 0, stream>>>(wq, wk, wv, wqb, wkb, wvb);
  k_projqk<<<dim3(64, 4), 256, 0, stream>>>(y, wqb, wkb, bq, bk, q, ktp);
  k_projv<<<dim3(64, 4), 512, 0, stream>>>(x, wvb, bv, vp);
  k_sminv<<<dim3(128, 4), 512, 0, stream>>>(q, ktp, inv);
  k_fused<<<256, 512, 0, stream>>>(q, ktp, vp, inv, x, gamma, out, att);
}

// Round 17
// 257.559 us; speedup vs baseline: 1.4086x; 1.0079x over previous
//
#include <hip/hip_runtime.h>

// SelfAttn (SAGAN block): B=4, C=512, N=4096, C8=64
// out = gamma * (V @ softmax(Q K^T)^T) + x ; also outputs attention [B,N,N].
// R17: k_sminv folded into k_fused as an inline pass-1 (R8-proven pattern,
// packed-kt loads). One kernel fewer; kt warmed in L2 for pass 2.

#define BB 4
#define CC 512
#define NN 4096
#define C8V 64

typedef __bf16 bf16x8 __attribute__((ext_vector_type(8)));
typedef float f32x4 __attribute__((ext_vector_type(4)));
typedef float f32x4v __attribute__((ext_vector_type(4)));
typedef unsigned short u16x8 __attribute__((ext_vector_type(8)));

#if __has_builtin(__builtin_amdgcn_exp2f)
#define EXP2(x) __builtin_amdgcn_exp2f(x)
#else
#define EXP2(x) exp2f(x)
#endif

#define MFMA16(a, b, c) __builtin_amdgcn_mfma_f32_16x16x32_bf16((a), (b), (c), 0, 0, 0)

__device__ __forceinline__ unsigned short f2b(float f) {
  union { float f; unsigned u; } x; x.f = f;
  unsigned u = x.u;
  u += 0x7fffu + ((u >> 16) & 1u);   // RNE round to bf16
  return (unsigned short)(u >> 16);
}

__device__ __forceinline__ float b2f(unsigned short s) {
  union { unsigned u; float f; } x; x.u = ((unsigned)s) << 16;
  return x.f;
}

__device__ __forceinline__ bf16x8 ldb8(const unsigned short* p) {
  return *reinterpret_cast<const bf16x8*>(p);
}

// ---------------- weights fp32 -> bf16 ----------------
__global__ __launch_bounds__(256) void k_cvt_w(
    const float* __restrict__ wq, const float* __restrict__ wk, const float* __restrict__ wv,
    unsigned short* __restrict__ wqb, unsigned short* __restrict__ wkb, unsigned short* __restrict__ wvb) {
  int i = blockIdx.x * 256 + threadIdx.x;
  if (i < 32768)        wqb[i] = f2b(wq[i]);
  else if (i < 65536)   wkb[i - 32768] = f2b(wk[i - 32768]);
  else if (i < 327680)  wvb[i - 65536] = f2b(wv[i - 65536]);
}

// ---------------- q + kt projection, straight from y ----------------
__global__ __launch_bounds__(256) void k_projqk(
    const float* __restrict__ y,
    const unsigned short* __restrict__ wqb, const unsigned short* __restrict__ wkb,
    const float* __restrict__ bq, const float* __restrict__ bk,
    unsigned short* __restrict__ q, unsigned short* __restrict__ ktp) {
  __shared__ unsigned short ytile[64][130];
  int b = blockIdx.y, n0 = blockIdx.x * 64;
  int t = threadIdx.x, w = t >> 6, l = t & 63, lr = l & 15, lk = l >> 4;
  const float* yb = y + (size_t)b * CC * NN;

  f32x4 qacc[4] = {}, kacc[4] = {};
  for (int slab = 0; slab < 4; slab++) {
    int cs = slab * 128;
#pragma unroll
    for (int r = 0; r < 8; r++) {                 // stage 128c x 64n
      int idx = t + r * 256, c = idx >> 4, n4 = (idx & 15) * 4;
      f32x4v v4 = *reinterpret_cast<const f32x4v*>(&yb[(size_t)(cs + c) * NN + n0 + n4]);
      ytile[n4 + 0][c] = f2b(v4.x); ytile[n4 + 1][c] = f2b(v4.y);
      ytile[n4 + 2][c] = f2b(v4.z); ytile[n4 + 3][c] = f2b(v4.w);
    }
    __syncthreads();
#pragma unroll
    for (int ks = 0; ks < 4; ks++) {
      bf16x8 a = *reinterpret_cast<const bf16x8*>(&ytile[w * 16 + lr][ks * 32 + lk * 8]);
      int cgl = cs + ks * 32 + lk * 8;
#pragma unroll
      for (int cg = 0; cg < 4; cg++) {
        qacc[cg] = MFMA16(a, ldb8(wqb + (size_t)(cg * 16 + lr) * CC + cgl), qacc[cg]);
        kacc[cg] = MFMA16(a, ldb8(wkb + (size_t)(cg * 16 + lr) * CC + cgl), kacc[cg]);
      }
    }
    __syncthreads();
  }
#pragma unroll
  for (int cg = 0; cg < 4; cg++) {
    int o = cg * 16 + lr;
    float bqv = bq[o], bkv = bk[o];
#pragma unroll
    for (int i = 0; i < 4; i++) {
      int n = n0 + w * 16 + lk * 4 + i;
      q[(size_t)(b * NN + n) * C8V + o] = f2b((qacc[cg][i] + bqv) * 1.44269504088896f);
      ktp[((size_t)(b * 256 + (n >> 4)) * 2 + (o >> 5)) * 512 + (n & 15) * 32 + (o & 31)] =
          f2b(kacc[cg][i] + bkv);
    }
  }
}

// ---------------- v projection, straight from x, packed output ----------------
__global__ __launch_bounds__(512) void k_projv(
    const float* __restrict__ x, const unsigned short* __restrict__ wvb,
    const float* __restrict__ bv, unsigned short* __restrict__ vp) {
  __shared__ unsigned short xtile[64][130];
  int b = blockIdx.y, n0 = blockIdx.x * 64;
  int t = threadIdx.x, w = t >> 6, l = t & 63, lr = l & 15, lk = l >> 4;
  const float* xb = x + (size_t)b * CC * NN;
  int c0w = w * 64;

  f32x4 acc[4][4] = {};
  for (int slab = 0; slab < 4; slab++) {
    int cs = slab * 128;
#pragma unroll
    for (int r = 0; r < 4; r++) {                 // stage 128c x 64n
      int idx = t + r * 512, c = idx >> 4, n4 = (idx & 15) * 4;
      f32x4v v4 = *reinterpret_cast<const f32x4v*>(&xb[(size_t)(cs + c) * NN + n0 + n4]);
      xtile[n4 + 0][c] = f2b(v4.x); xtile[n4 + 1][c] = f2b(v4.y);
      xtile[n4 + 2][c] = f2b(v4.z); xtile[n4 + 3][c] = f2b(v4.w);
    }
    __syncthreads();
#pragma unroll
    for (int ks = 0; ks < 4; ks++) {
      bf16x8 bfr[4];
#pragma unroll
      for (int cg = 0; cg < 4; cg++)
        bfr[cg] = *reinterpret_cast<const bf16x8*>(&xtile[cg * 16 + lr][ks * 32 + lk * 8]);
#pragma unroll
      for (int rg = 0; rg < 4; rg++) {
        bf16x8 a = ldb8(wvb + (size_t)(c0w + rg * 16 + lr) * CC + cs + ks * 32 + lk * 8);
#pragma unroll
        for (int cg = 0; cg < 4; cg++)
          acc[rg][cg] = MFMA16(a, bfr[cg], acc[rg][cg]);
      }
    }
    __syncthreads();
  }
#pragma unroll
  for (int rg = 0; rg < 4; rg++)
#pragma unroll
    for (int i = 0; i < 4; i++) {
      int c = c0w + rg * 16 + lk * 4 + i;
      float bias = bv[c];
#pragma unroll
      for (int cg = 0; cg < 4; cg++) {
        int n = n0 + cg * 16 + lr;
        vp[((size_t)(b * 64 + (n >> 6)) * 2 + ((n >> 5) & 1)) * 16384 + c * 32 + (n & 31)] =
            f2b(acc[rg][cg][i] + bias);
      }
    }
}

// ---------------- fused: pass1 rowsums + att write + PV + epilogue ----------------
// Grid 256 (1 block/CU), XCD-pinned. Pass 1 inline (was k_sminv): wave w
// covers rows rg=w>>1, col-half nh=w&1 of every chunk; 16-lane shfl reduce;
// one LDS combine barrier. Pass 2 = R16 pipeline (FIFO-clean, register
// double-buffered kt/v, lgkm-only barriers, plain wide stores, packed loads).
__global__ __launch_bounds__(512, 2) void k_fused(const unsigned short* __restrict__ q,
                                                  const unsigned short* __restrict__ ktp,
                                                  const unsigned short* __restrict__ vp,
                                                  const float* __restrict__ x,
                                                  const float* __restrict__ gamma,
                                                  float* __restrict__ out,
                                                  float* __restrict__ att) {
  __shared__ unsigned short smP[2][64 * 64];   // 2 x 8 KiB P tiles
  __shared__ float psum[8][16];

  int bid = blockIdx.x;
  int b = (bid & 7) >> 1;                       // XCD id = bid % 8
  int m0 = ((bid >> 3) * 2 + (bid & 1)) * 64;   // 64 m-tiles per batch
  int t = threadIdx.x, w = t >> 6, l = t & 63, lr = l & 15, lk = l >> 4;
  int rg = w >> 1, nh = w & 1;                  // QK^T: rows rg*16.., col-half nh
  int c0w = w * 64;                             // PV: 64 c-rows per wave
  int mrow = t >> 3, col8 = t & 7;              // ATTST: row, col-octet

  float* ab = att + (size_t)b * NN * NN;

  const unsigned short* qp = q + (size_t)(b * NN + m0 + rg * 16 + lr) * C8V + lk * 8;
  bf16x8 aq0 = ldb8(qp), aq1 = ldb8(qp + 32);

  // ---- pass 1: row sums (rows rg*16+lk*4+i, this wave's col-half) ----
  float lsum[4] = {0.f, 0.f, 0.f, 0.f};
  for (int jt = 0; jt < 64; jt++) {
    f32x4 acc2[2] = {};
#pragma unroll
    for (int cg = 0; cg < 2; cg++) {
      size_t base = ((size_t)(b * 256 + jt * 4 + nh * 2 + cg) * 2) * 512 + lr * 32 + lk * 8;
      acc2[cg] = MFMA16(aq0, ldb8(ktp + base), acc2[cg]);
      acc2[cg] = MFMA16(aq1, ldb8(ktp + base + 512), acc2[cg]);
    }
#pragma unroll
    for (int i = 0; i < 4; i++)
      lsum[i] += EXP2(acc2[0][i]) + EXP2(acc2[1][i]);
  }
#pragma unroll
  for (int i = 0; i < 4; i++) {
#pragma unroll
    for (int mm = 1; mm < 16; mm <<= 1) lsum[i] += __shfl_xor(lsum[i], mm);
  }
  if (lr == 0) {
#pragma unroll
    for (int i = 0; i < 4; i++) psum[w][lk * 4 + i] = lsum[i];
  }
  __syncthreads();
  f32x4v invv;
#pragma unroll
  for (int i = 0; i < 4; i++)
    invv[i] = 1.0f / (psum[rg * 2][lk * 4 + i] + psum[rg * 2 + 1][lk * 4 + i]);

#define LDKT(D, JT)                                                            \
  _Pragma("unroll")                                                            \
  for (int cg = 0; cg < 2; cg++) {                                             \
    size_t base = ((size_t)(b * 256 + (JT) * 4 + nh * 2 + cg) * 2) * 512 +     \
                  lr * 32 + lk * 8;                                            \
    D[cg * 2] = ldb8(ktp + base);                                              \
    D[cg * 2 + 1] = ldb8(ktp + base + 512);                                    \
  }

#define LDV(D, JT)                                                             \
  _Pragma("unroll")                                                            \
  for (int rg2 = 0; rg2 < 4; rg2++) {                                          \
    size_t vbase = ((size_t)(b * 64 + (JT)) * 2) * 16384 +                     \
                   (c0w + rg2 * 16 + lr) * 32 + lk * 8;                        \
    D[rg2 * 2] = ldb8(vp + vbase);                                             \
    D[rg2 * 2 + 1] = ldb8(vp + vbase + 16384);                                 \
  }

// QK^T from REGISTER kt set -> softmax -> bf16 P into LDS buf (no globals)
#define QKSM(KT, BUF)                                                          \
  {                                                                            \
    char* pbuf = reinterpret_cast<char*>(&smP[BUF][0]);                        \
    _Pragma("unroll")                                                          \
    for (int cg = 0; cg < 2; cg++) {                                           \
      f32x4 z = {};                                                            \
      z = MFMA16(aq0, KT[cg * 2], z);                                          \
      z = MFMA16(aq1, KT[cg * 2 + 1], z);                                      \
      int nl = nh * 32 + cg * 16 + lr;                                         \
      _Pragma("unroll")                                                        \
      for (int i = 0; i < 4; i++) {                                            \
        int ml = rg * 16 + lk * 4 + i;                                         \
        float p = EXP2(z[i]) * invv[i];                                        \
        *reinterpret_cast<unsigned short*>(                                    \
            pbuf + ml * 128 + ((nl * 2) ^ ((ml & 7) << 4))) = f2b(p);          \
      }                                                                        \
    }                                                                          \
  }

// att store: LDS P readback -> fp32 -> 2x dwordx4 PLAIN store (via L2)
#define ATTST(BUF, JT)                                                         \
  {                                                                            \
    const char* pr = reinterpret_cast<const char*>(&smP[BUF][0]);              \
    u16x8 raw = *reinterpret_cast<const u16x8*>(                               \
        pr + mrow * 128 + ((col8 * 16) ^ ((mrow & 7) << 4)));                  \
    f32x4v lo, hi;                                                             \
    lo.x = b2f(raw[0]); lo.y = b2f(raw[1]); lo.z = b2f(raw[2]);                \
    lo.w = b2f(raw[3]); hi.x = b2f(raw[4]); hi.y = b2f(raw[5]);                \
    hi.z = b2f(raw[6]); hi.w = b2f(raw[7]);                                    \
    float* dst = &ab[(size_t)(m0 + mrow) * NN + (JT) * 64 + col8 * 8];         \
    *reinterpret_cast<f32x4v*>(dst) = lo;                                      \
    *reinterpret_cast<f32x4v*>(dst + 4) = hi;                                  \
  }

#define PV(VR, BUF)                                                            \
  {                                                                            \
    const char* pr = reinterpret_cast<const char*>(&smP[BUF][0]);              \
    __builtin_amdgcn_s_setprio(1);                                             \
    _Pragma("unroll")                                                          \
    for (int ks = 0; ks < 2; ks++) {                                           \
      bf16x8 bfr[4];                                                           \
      _Pragma("unroll")                                                        \
      for (int cg = 0; cg < 4; cg++) {                                         \
        int mr = cg * 16 + lr;                                                 \
        bfr[cg] = *reinterpret_cast<const bf16x8*>(                            \
            pr + mr * 128 + ((ks * 64 + lk * 16) ^ ((mr & 7) << 4)));          \
      }                                                                        \
      _Pragma("unroll")                                                        \
      for (int rg2 = 0; rg2 < 4; rg2++)                                        \
        _Pragma("unroll")                                                      \
        for (int cg = 0; cg < 4; cg++)                                         \
          acc[rg2][cg] = MFMA16(VR[rg2 * 2 + ks], bfr[cg], acc[rg2][cg]);      \
    }                                                                          \
    __builtin_amdgcn_s_setprio(0);                                             \
  }

#define SB() __builtin_amdgcn_sched_barrier(0);

#define SYNC_NODRAIN()                                   \
  asm volatile("s_waitcnt lgkmcnt(0)" ::: "memory");     \
  __builtin_amdgcn_s_barrier();                          \
  __builtin_amdgcn_sched_barrier(0);

  f32x4 acc[4][4] = {};
  bf16x8 ktA[4], ktB[4];   // kt sets: even chunks -> A, odd -> B
  bf16x8 vA[8], vB[8];     // v sets: even chunks -> A, odd -> B

  // prologue: kt(0)->A, v(0)->A, P(0)->buf0, kt(1)->B
  LDKT(ktA, 0);
  LDV(vA, 0);
  QKSM(ktA, 0);
  LDKT(ktB, 1);
  SYNC_NODRAIN();

// one period; CUR = chunk parity of g
#define BODY(G, KTF, VN, KTC, VC, CUR)                                         \
  {                                                                            \
    int g = (G);                                                               \
    if (g < 62) LDKT(KTF, g + 2);        /* loads FIRST */                     \
    if (g < 63) LDV(VN, g + 1);                                                \
    SB();                                                                      \
    ATTST(CUR, g);                       /* stores after loads */              \
    SB();                                                                      \
    if (g < 63) QKSM(KTC, (CUR) ^ 1);    /* reg MFMA + LDS write */            \
    PV(VC, CUR);                                                               \
    SYNC_NODRAIN();                                                            \
  }

  for (int g2 = 0; g2 < 64; g2 += 2) {
    BODY(g2,     ktA, vB, ktB, vA, 0);
    BODY(g2 + 1, ktB, vA, ktA, vB, 1);
  }
#undef LDKT
#undef LDV
#undef QKSM
#undef ATTST
#undef PV
#undef SB
#undef SYNC_NODRAIN
#undef BODY

  // ---- epilogue: out = gamma*acc + x (plain stores via L2) ----
  float gm = gamma[0];
  const float* xb = x + (size_t)b * CC * NN;
  float* ob = out + (size_t)b * CC * NN;
#pragma unroll
  for (int rg2 = 0; rg2 < 4; rg2++)
#pragma unroll
    for (int i = 0; i < 4; i++) {
      int row = c0w + rg2 * 16 + lk * 4 + i;
#pragma unroll
      for (int cg = 0; cg < 4; cg++) {
        int col = m0 + cg * 16 + lr;
        size_t off = (size_t)row * NN + col;
        float xv = __builtin_nontemporal_load(&xb[off]);
        ob[off] = gm * acc[rg2][cg][i] + xv;
      }
    }
}

extern "C" void kernel_launch(void* const* d_in, const int* in_sizes, int n_in,
                              void* d_out, int out_size, void* d_ws, size_t ws_size,
                              hipStream_t stream) {
  const float* x  = (const float*)d_in[0];
  const float* y  = (const float*)d_in[1];
  const float* wq = (const float*)d_in[2];
  const float* bq = (const float*)d_in[3];
  const float* wk = (const float*)d_in[4];
  const float* bk = (const float*)d_in[5];
  const float* wv = (const float*)d_in[6];
  const float* bv = (const float*)d_in[7];
  const float* gamma = (const float*)d_in[8];

  float* out = (float*)d_out;
  float* att = out + (size_t)BB * CC * NN;   // attention region of d_out

  // workspace layout (bytes)
  char* ws = (char*)d_ws;
  unsigned short* q   = (unsigned short*)(ws);                 // 2 MiB  [b*N][64]
  unsigned short* ktp = (unsigned short*)(ws + 2097152);       // 2 MiB  packed kt
  unsigned short* vp  = (unsigned short*)(ws + 4194304);       // 16 MiB packed v
  unsigned short* wqb = (unsigned short*)(ws + 20971520);      // 64 KiB
  unsigned short* wkb = (unsigned short*)(ws + 21037056);      // 64 KiB
  unsigned short* wvb = (unsigned short*)(ws + 21102592);      // 512 KiB
  if (ws_size < 21626880u) return;  // insufficient scratch -> fail loudly

  k_cvt_w<<<1280, 256, 0, stream>>>(wq, wk, wv, wqb, wkb, wvb);
  k_projqk<<<dim3(64, 4), 256, 0, stream>>>(y, wqb, wkb, bq, bk, q, ktp);
  k_projv<<<dim3(64, 4), 512, 0, stream>>>(x, wvb, bv, vp);
  k_fused<<<256, 512, 0, stream>>>(q, ktp, vp, x, gamma, out, att);
}